// Round 2
// 445.385 us; speedup vs baseline: 1.0107x; 1.0107x over previous
//
#include <hip/hip_runtime.h>

// Problem constants: X is [80,80,64] fp32; N=6400 nodes, C=64 features.
#define HH 80
#define NN 6400
#define CC 64
#define THR (1.0f / 6400.0f)   // = mean of softmax row, exactly 1/N

typedef _Float16 f16x8 __attribute__((ext_vector_type(8)));
typedef float float4v __attribute__((ext_vector_type(4)));

// ---------------------------------------------------------------------------
// prep: split X into f16 hi/lo (for 3-MFMA fp32-accurate matmul), row norms,
// global max norm via int-pattern atomicMax (positive floats order as ints;
// 0xAAAAAAAA poison is negative so no init needed), zero denom accumulators.
// Grid: 1600 x 256 (one thread per element; each wave == one row of 64).
// NOTE: workspace is packed to EXACTLY 1689604 bytes (prior passing layout).
// Do not add workspace buffers past nmax — ws_size is tight; overflow lands
// in adjacent allocations (caused the round-1 NaN via a corrupted Stab).
// ---------------------------------------------------------------------------
__global__ __launch_bounds__(256) void prep_kernel(
    const float* __restrict__ X,
    _Float16* __restrict__ Xhi, _Float16* __restrict__ Xlo,
    float* __restrict__ norms, float* __restrict__ denom,
    int* __restrict__ nmax)
{
    const int id = blockIdx.x * 256 + threadIdx.x;
    const float x = X[id];
    const _Float16 h = (_Float16)x;
    const float lo = x - (float)h;
    Xhi[id] = h;
    Xlo[id] = (_Float16)lo;

    float s = x * x;
#pragma unroll
    for (int m = 1; m < 64; m <<= 1) s += __shfl_xor(s, m, 64);
    const int lane = threadIdx.x & 63;
    if (lane == 0) {
        const int row = id >> 6;           // 64 elements per row == one wave
        norms[row] = s;
        atomicMax(nmax, __float_as_int(s));
    }
    if (id < NN) denom[id] = 0.f;          // re-zeroed every call (ws poisoned)
}

// ---------------------------------------------------------------------------
// pass1: denom[i] = sum_j exp(s_ij - mhat_i), mhat_i = sqrt(norms_i * nmax)
// (Cauchy-Schwarz upper bound on the row max; mhat - truemax <= M^2/4 ~ 29,
// so denom >= e^-29 — fp32 safe, no online rescaling needed).
// Split-f16 matmul: s = Al*Bh + Ah*Bl + Ah*Bh (lo*lo term ~2^-22, dropped).
// Block = 4 waves, each wave owns 64 rows (4 row-tiles of A in registers so
// B-fragment loads amortize 4x). Grid (25 row-groups, 25 col-splits of 256).
// Column permutation within the tile is irrelevant here (we SUM over j).
// ---------------------------------------------------------------------------
__global__ __launch_bounds__(256) void pass1_kernel(
    const _Float16* __restrict__ Xhi, const _Float16* __restrict__ Xlo,
    const float* __restrict__ norms, const int* __restrict__ nmaxp,
    float* __restrict__ denom)
{
    const int tid = threadIdx.x;
    const int wave = tid >> 6, lane = tid & 63;
    const int q = lane >> 4, n16 = lane & 15;
    const int i0 = blockIdx.x * 256 + wave * 64;
    const int j0 = blockIdx.y * 256;
    const float nmax = __int_as_float(*nmaxp);

    // A fragments: A[m=lane&15][k = q*8 + j], two 32-wide k-chunks, hi+lo
    f16x8 Ah[4][2], Al[4][2];
#pragma unroll
    for (int rt = 0; rt < 4; rt++) {
        const int row = i0 + rt * 16 + n16;
#pragma unroll
        for (int c = 0; c < 2; c++) {
            const int off = row * CC + c * 32 + q * 8;
            Ah[rt][c] = *(const f16x8*)(Xhi + off);
            Al[rt][c] = *(const f16x8*)(Xlo + off);
        }
    }
    // mhat for the 16 (row-tile, reg) rows this lane's C-fragment touches
    float mh[4][4];
#pragma unroll
    for (int rt = 0; rt < 4; rt++)
#pragma unroll
        for (int r = 0; r < 4; r++)
            mh[rt][r] = sqrtf(norms[i0 + rt * 16 + q * 4 + r] * nmax);

    float cs[4][4];
#pragma unroll
    for (int rt = 0; rt < 4; rt++)
#pragma unroll
        for (int r = 0; r < 4; r++) cs[rt][r] = 0.f;

    for (int ct = 0; ct < 16; ct++) {
        const int col = j0 + ct * 16 + n16;   // B[k][n]: n=lane&15 -> X row j
        f16x8 Bh[2], Bl[2];
#pragma unroll
        for (int c = 0; c < 2; c++) {
            const int off = col * CC + c * 32 + q * 8;
            Bh[c] = *(const f16x8*)(Xhi + off);
            Bl[c] = *(const f16x8*)(Xlo + off);
        }
#pragma unroll
        for (int rt = 0; rt < 4; rt++) {
            float4v acc = {0.f, 0.f, 0.f, 0.f};
#pragma unroll
            for (int c = 0; c < 2; c++) {
                acc = __builtin_amdgcn_mfma_f32_16x16x32_f16(Al[rt][c], Bh[c], acc, 0, 0, 0);
                acc = __builtin_amdgcn_mfma_f32_16x16x32_f16(Ah[rt][c], Bl[c], acc, 0, 0, 0);
                acc = __builtin_amdgcn_mfma_f32_16x16x32_f16(Ah[rt][c], Bh[c], acc, 0, 0, 0);
            }
#pragma unroll
            for (int r = 0; r < 4; r++)
                cs[rt][r] += __expf(acc[r] - mh[rt][r]);
        }
    }
    // reduce the 16 lanes of each quad-group (same row set), one atomic/row
#pragma unroll
    for (int rt = 0; rt < 4; rt++)
#pragma unroll
        for (int r = 0; r < 4; r++) {
            float v = cs[rt][r];
            v += __shfl_xor(v, 1, 64);
            v += __shfl_xor(v, 2, 64);
            v += __shfl_xor(v, 4, 64);
            v += __shfl_xor(v, 8, 64);
            if (n16 == 0)
                atomicAdd(&denom[i0 + rt * 16 + q * 4 + r], v);
        }
}

// ---------------------------------------------------------------------------
// pass2: recompute s tile, write As = thresh(exp(s-mhat)/denom) and the fully
// analytic Ad = exp(-d2/2) / (S(r_i)S(c_i) - 1), diag 0.
// B-operand column mapping is permuted — col-tile ct feeds X row
// (j0 + 4*n16 + ct) — so each lane's four ct-fragments are 4 CONTIGUOUS
// output columns. Epilogue packs float4 and emits nontemporal dwordx4 stores
// for both As and Ad (4x fewer store instrs; no cache allocate for 327 MB of
// streaming output). Stab is computed in-block (shared) as in the original
// passing version — A-fragment loads are hoisted above it so the 80-deep
// serial __expf chain overlaps the 16 in-flight global loads.
// Block covers 256 rows x 64 cols. Grid (25, 100) = 2500 blocks.
// ---------------------------------------------------------------------------
__global__ __launch_bounds__(256) void pass2_kernel(
    const _Float16* __restrict__ Xhi, const _Float16* __restrict__ Xlo,
    const float* __restrict__ norms, const int* __restrict__ nmaxp,
    const float* __restrict__ denom,
    float* __restrict__ Ad, float* __restrict__ As)
{
    __shared__ float Stab[HH];              // S(t) = sum_k exp(-(t-k)^2/2)
    __shared__ float sMh[256], sRden[256], sRec[256];
    __shared__ int   sRC[256];
    const int tid = threadIdx.x;
    const int i0 = blockIdx.x * 256;
    const int j0 = blockIdx.y * 64;

    const int wave = tid >> 6, lane = tid & 63;
    const int q = lane >> 4, n16 = lane & 15;
    const int iw = i0 + wave * 64;
    const int jb = j0 + 4 * n16;            // this lane's 4 contiguous cols

    // A-fragment global loads first (no LDS dependence) — they stay in
    // flight while the Stab exp chain below runs.
    f16x8 Ah[4][2], Al[4][2];
#pragma unroll
    for (int rt = 0; rt < 4; rt++) {
        const int row = iw + rt * 16 + n16;
#pragma unroll
        for (int c = 0; c < 2; c++) {
            const int off = row * CC + c * 32 + q * 8;
            Ah[rt][c] = *(const f16x8*)(Xhi + off);
            Al[rt][c] = *(const f16x8*)(Xlo + off);
        }
    }

    if (tid < HH) {
        float s = 0.f;
        for (int k = 0; k < HH; k++) {
            const float d = (float)(tid - k);
            s += __expf(-0.5f * d * d);
        }
        Stab[tid] = s;
    }
    __syncthreads();
    {
        const int i = i0 + tid;
        const float nmax = __int_as_float(*nmaxp);
        sMh[tid] = sqrtf(norms[i] * nmax);
        sRden[tid] = 1.0f / denom[i];
        const int r = i / HH, c = i - r * HH;
        sRec[tid] = 1.0f / (Stab[r] * Stab[c] - 1.0f);   // Ad row normalizer
        sRC[tid] = (r << 8) | c;
    }
    __syncthreads();

    float4v acc[4][4];
#pragma unroll
    for (int rt = 0; rt < 4; rt++)
#pragma unroll
        for (int ct = 0; ct < 4; ct++)
            acc[rt][ct] = (float4v){0.f, 0.f, 0.f, 0.f};

#pragma unroll
    for (int ct = 0; ct < 4; ct++) {
        const int col = jb + ct;            // permuted B mapping (see header)
        f16x8 Bh[2], Bl[2];
#pragma unroll
        for (int c = 0; c < 2; c++) {
            const int off = col * CC + c * 32 + q * 8;
            Bh[c] = *(const f16x8*)(Xhi + off);
            Bl[c] = *(const f16x8*)(Xlo + off);
        }
#pragma unroll
        for (int rt = 0; rt < 4; rt++) {
#pragma unroll
            for (int c = 0; c < 2; c++) {
                acc[rt][ct] = __builtin_amdgcn_mfma_f32_16x16x32_f16(Al[rt][c], Bh[c], acc[rt][ct], 0, 0, 0);
                acc[rt][ct] = __builtin_amdgcn_mfma_f32_16x16x32_f16(Ah[rt][c], Bl[c], acc[rt][ct], 0, 0, 0);
                acc[rt][ct] = __builtin_amdgcn_mfma_f32_16x16x32_f16(Ah[rt][c], Bh[c], acc[rt][ct], 0, 0, 0);
            }
        }
    }

    // epilogue: per-lane column coords for the 4 contiguous cols
    int rj[4], cj[4];
#pragma unroll
    for (int ct = 0; ct < 4; ct++) {
        const int j = jb + ct;
        rj[ct] = j / HH;
        cj[ct] = j - rj[ct] * HH;
    }
#pragma unroll
    for (int rt = 0; rt < 4; rt++) {
#pragma unroll
        for (int r = 0; r < 4; r++) {
            const int il = wave * 64 + rt * 16 + q * 4 + r;
            const int i = i0 + il;
            const float mhv = sMh[il], rden = sRden[il], rec = sRec[il];
            const int rc = sRC[il];
            const int ri = rc >> 8, ci = rc & 255;
            float4v as4, ad4;
#pragma unroll
            for (int ct = 0; ct < 4; ct++) {
                float e = __expf(acc[rt][ct][r] - mhv) * rden;
                if (e < THR) e = 0.f;       // As < 1/N -> 0 (avg == 1/N exact)
                as4[ct] = e;
                const int dr = ri - rj[ct], dc = ci - cj[ct];
                const float d2 = (float)(dr * dr + dc * dc);
                float ad = __expf(-0.5f * d2) * rec;
                if (i == jb + ct) ad = 0.f; // diagonal stays 0
                ad4[ct] = ad;
            }
            __builtin_nontemporal_store(as4, (float4v*)(As + (size_t)i * NN + jb));
            __builtin_nontemporal_store(ad4, (float4v*)(Ad + (size_t)i * NN + jb));
        }
    }
}

extern "C" void kernel_launch(void* const* d_in, const int* in_sizes, int n_in,
                              void* d_out, int out_size, void* d_ws, size_t ws_size,
                              hipStream_t stream) {
    const float* X = (const float*)d_in[0];
    float* Ad = (float*)d_out;                    // output 0: [N,N]
    float* As = Ad + (size_t)NN * NN;             // output 1: [N,N]

    // workspace layout (exactly 1689604 B — the prior passing layout; tight)
    char* w = (char*)d_ws;
    _Float16* Xhi = (_Float16*)(w);               // 819200 B
    _Float16* Xlo = (_Float16*)(w + 819200);      // 819200 B
    float* norms  = (float*)(w + 1638400);        // 25600 B
    float* denom  = (float*)(w + 1664000);        // 25600 B
    int*   nmax   = (int*)(w + 1689600);          // 4 B

    prep_kernel<<<dim3((NN * CC) / 256), dim3(256), 0, stream>>>(
        X, Xhi, Xlo, norms, denom, nmax);
    pass1_kernel<<<dim3(25, 25), dim3(256), 0, stream>>>(
        Xhi, Xlo, norms, nmax, denom);
    pass2_kernel<<<dim3(25, 100), dim3(256), 0, stream>>>(
        Xhi, Xlo, norms, nmax, denom, Ad, As);
}

// Round 4
// 380.987 us; speedup vs baseline: 1.1815x; 1.1690x over previous
//
#include <hip/hip_runtime.h>

// Problem constants: X is [80,80,64] fp32; N=6400 nodes, C=64 features.
#define HH 80
#define NN 6400
#define CC 64
#define THR (1.0f / 6400.0f)   // = mean of softmax row, exactly 1/N

typedef _Float16 f16x8 __attribute__((ext_vector_type(8)));
typedef _Float16 f16x4 __attribute__((ext_vector_type(4)));
typedef float float4v __attribute__((ext_vector_type(4)));

// S(t) = sum_k exp(-(t-k)^2/2) over k=0..79. Data-independent; converges to
// 1 + 2*P(13) for interior t (terms beyond |d|=13 are < 1e-37). Baked as
// literals (double-accurate, rounded): replaces an 80-deep serial __expf
// chain per block. Diff vs the old fp32 on-device sum ~1e-7 << 2e-2 tol.
__device__ __forceinline__ float stab_of(int t) {
    const int m = min(t, 79 - t);
    float v = 2.5066282880428827f;          // m >= 6 (converged)
    if      (m == 0) v = 1.7533141440214413f;
    else if (m == 1) v = 2.3598448037340748f;
    else if (m == 2) v = 2.4951800869706875f;
    else if (m == 3) v = 2.5062890835089298f;
    else if (m == 4) v = 2.5066245461368322f;
    else if (m == 5) v = 2.5066282727900043f;
    return v;
}

// ---------------------------------------------------------------------------
// prep: split X into f16 hi/lo (for 3-MFMA fp32-accurate matmul), row norms,
// global max norm. Vectorized: 4 floats/thread (float4 in, f16x4 out), so
// grid is 400 blocks. Row (64 floats) = 16 consecutive lanes -> 4-stage
// shuffle row-sum; then wave-max + LDS block-max -> ONE atomicMax per block
// (was 6400 same-address atomics). 0xAAAAAAAA poison is negative so the
// int-pattern atomicMax needs no init. denom re-zeroed every call.
// NOTE: workspace is packed to EXACTLY 1689604 bytes. Do not add buffers
// past nmax — overflow lands in adjacent allocations (round-1 NaN lesson).
// ---------------------------------------------------------------------------
__global__ __launch_bounds__(256) void prep_kernel(
    const float* __restrict__ X,
    _Float16* __restrict__ Xhi, _Float16* __restrict__ Xlo,
    float* __restrict__ norms, float* __restrict__ denom,
    int* __restrict__ nmax)
{
    __shared__ float sWmax[4];
    const int t = blockIdx.x * 256 + threadIdx.x;   // [0, 102400)
    const float4v x = *(const float4v*)(X + 4 * (size_t)t);
    f16x4 h, l;
    float s = 0.f;
#pragma unroll
    for (int e = 0; e < 4; e++) {
        const float xe = x[e];
        const _Float16 he = (_Float16)xe;
        h[e] = he;
        l[e] = (_Float16)(xe - (float)he);
        s += xe * xe;
    }
    *(f16x4*)(Xhi + 4 * (size_t)t) = h;
    *(f16x4*)(Xlo + 4 * (size_t)t) = l;

    // row sum within each 16-lane group (one row = 16 threads * 4 elems)
    s += __shfl_xor(s, 1, 64);
    s += __shfl_xor(s, 2, 64);
    s += __shfl_xor(s, 4, 64);
    s += __shfl_xor(s, 8, 64);
    const int lane = threadIdx.x & 63;
    if ((lane & 15) == 0) norms[t >> 4] = s;

    // wave max of its 4 row sums, then block max, one atomic per block
    float m = s;
    m = fmaxf(m, __shfl_xor(m, 16, 64));
    m = fmaxf(m, __shfl_xor(m, 32, 64));
    if (lane == 0) sWmax[threadIdx.x >> 6] = m;
    __syncthreads();
    if (threadIdx.x == 0) {
        const float bm = fmaxf(fmaxf(sWmax[0], sWmax[1]),
                               fmaxf(sWmax[2], sWmax[3]));
        atomicMax(nmax, __float_as_int(bm));
    }
    if (t < NN) denom[t] = 0.f;
}

// ---------------------------------------------------------------------------
// pass1: denom[i] = sum_j exp(s_ij - mhat_i), mhat_i = sqrt(norms_i * nmax)
// (Cauchy-Schwarz upper bound on the row max; mhat - truemax <= M^2/4 ~ 29,
// so denom >= e^-29 — fp32 safe, no online rescaling needed).
// Split-f16 matmul: s = Al*Bh + Ah*Bl + Ah*Bh (lo*lo term ~2^-22, dropped).
// Block = 4 waves, each wave owns 64 rows. Grid (25, 25). Unchanged — it is
// already near its compute floor (~6-8 us).
// ---------------------------------------------------------------------------
__global__ __launch_bounds__(256) void pass1_kernel(
    const _Float16* __restrict__ Xhi, const _Float16* __restrict__ Xlo,
    const float* __restrict__ norms, const int* __restrict__ nmaxp,
    float* __restrict__ denom)
{
    const int tid = threadIdx.x;
    const int wave = tid >> 6, lane = tid & 63;
    const int q = lane >> 4, n16 = lane & 15;
    const int i0 = blockIdx.x * 256 + wave * 64;
    const int j0 = blockIdx.y * 256;
    const float nmax = __int_as_float(*nmaxp);

    // A fragments: A[m=lane&15][k = q*8 + j], two 32-wide k-chunks, hi+lo
    f16x8 Ah[4][2], Al[4][2];
#pragma unroll
    for (int rt = 0; rt < 4; rt++) {
        const int row = i0 + rt * 16 + n16;
#pragma unroll
        for (int c = 0; c < 2; c++) {
            const int off = row * CC + c * 32 + q * 8;
            Ah[rt][c] = *(const f16x8*)(Xhi + off);
            Al[rt][c] = *(const f16x8*)(Xlo + off);
        }
    }
    // mhat for the 16 (row-tile, reg) rows this lane's C-fragment touches
    float mh[4][4];
#pragma unroll
    for (int rt = 0; rt < 4; rt++)
#pragma unroll
        for (int r = 0; r < 4; r++)
            mh[rt][r] = sqrtf(norms[i0 + rt * 16 + q * 4 + r] * nmax);

    float cs[4][4];
#pragma unroll
    for (int rt = 0; rt < 4; rt++)
#pragma unroll
        for (int r = 0; r < 4; r++) cs[rt][r] = 0.f;

    for (int ct = 0; ct < 16; ct++) {
        const int col = j0 + ct * 16 + n16;   // B[k][n]: n=lane&15 -> X row j
        f16x8 Bh[2], Bl[2];
#pragma unroll
        for (int c = 0; c < 2; c++) {
            const int off = col * CC + c * 32 + q * 8;
            Bh[c] = *(const f16x8*)(Xhi + off);
            Bl[c] = *(const f16x8*)(Xlo + off);
        }
#pragma unroll
        for (int rt = 0; rt < 4; rt++) {
            float4v acc = {0.f, 0.f, 0.f, 0.f};
#pragma unroll
            for (int c = 0; c < 2; c++) {
                acc = __builtin_amdgcn_mfma_f32_16x16x32_f16(Al[rt][c], Bh[c], acc, 0, 0, 0);
                acc = __builtin_amdgcn_mfma_f32_16x16x32_f16(Ah[rt][c], Bl[c], acc, 0, 0, 0);
                acc = __builtin_amdgcn_mfma_f32_16x16x32_f16(Ah[rt][c], Bh[c], acc, 0, 0, 0);
            }
#pragma unroll
            for (int r = 0; r < 4; r++)
                cs[rt][r] += __expf(acc[r] - mh[rt][r]);
        }
    }
    // reduce the 16 lanes of each quad-group (same row set), one atomic/row
#pragma unroll
    for (int rt = 0; rt < 4; rt++)
#pragma unroll
        for (int r = 0; r < 4; r++) {
            float v = cs[rt][r];
            v += __shfl_xor(v, 1, 64);
            v += __shfl_xor(v, 2, 64);
            v += __shfl_xor(v, 4, 64);
            v += __shfl_xor(v, 8, 64);
            if (n16 == 0)
                atomicAdd(&denom[i0 + rt * 16 + q * 4 + r], v);
        }
}

// ---------------------------------------------------------------------------
// pass2: recompute s tile, write As = thresh(exp(s-mhat)/denom) and the fully
// analytic Ad = exp(-d2/2) / (S(r_i)S(c_i) - 1), diag 0.
// B column mapping permuted (col-tile ct feeds X row jb+ct) so each lane's
// four ct-fragments are 4 CONTIGUOUS output columns -> packed dwordx4 stores.
// PLAIN stores (nt removed: it gave zero timed gain and is the suspect for
// the 20 ms profiling anomaly; the poison fill proves 6.26 TB/s through L2).
// Block now covers 256 rows x 256 cols via an inner jt loop of 4 x 64-col
// tiles: 625 blocks, 1 KB contiguous per row per block (DRAM page locality),
// 4x fewer prologues. Stab is baked (stab_of), no exp chain, single sync.
// ---------------------------------------------------------------------------
__global__ __launch_bounds__(256) void pass2_kernel(
    const _Float16* __restrict__ Xhi, const _Float16* __restrict__ Xlo,
    const float* __restrict__ norms, const int* __restrict__ nmaxp,
    const float* __restrict__ denom,
    float* __restrict__ Ad, float* __restrict__ As)
{
    __shared__ float sMh[256], sRden[256], sRec[256];
    __shared__ int   sRC[256];
    const int tid = threadIdx.x;
    const int i0 = blockIdx.x * 256;
    const int j0 = blockIdx.y * 256;

    const int wave = tid >> 6, lane = tid & 63;
    const int q = lane >> 4, n16 = lane & 15;
    const int iw = i0 + wave * 64;

    // A-fragment global loads first — in flight during the prologue.
    f16x8 Ah[4][2], Al[4][2];
#pragma unroll
    for (int rt = 0; rt < 4; rt++) {
        const int row = iw + rt * 16 + n16;
#pragma unroll
        for (int c = 0; c < 2; c++) {
            const int off = row * CC + c * 32 + q * 8;
            Ah[rt][c] = *(const f16x8*)(Xhi + off);
            Al[rt][c] = *(const f16x8*)(Xlo + off);
        }
    }

    {
        const int i = i0 + tid;
        const float nmax = __int_as_float(*nmaxp);
        sMh[tid] = sqrtf(norms[i] * nmax);
        sRden[tid] = 1.0f / denom[i];
        const int r = i / HH, c = i - r * HH;
        sRec[tid] = 1.0f / (stab_of(r) * stab_of(c) - 1.0f);
        sRC[tid] = (r << 8) | c;
    }
    __syncthreads();

    for (int jt = 0; jt < 4; jt++) {
        const int jb = j0 + jt * 64 + 4 * n16;  // this lane's 4 contig cols

        float4v acc[4][4];
#pragma unroll
        for (int rt = 0; rt < 4; rt++)
#pragma unroll
            for (int ct = 0; ct < 4; ct++)
                acc[rt][ct] = (float4v){0.f, 0.f, 0.f, 0.f};

#pragma unroll
        for (int ct = 0; ct < 4; ct++) {
            const int col = jb + ct;            // permuted B mapping
            f16x8 Bh[2], Bl[2];
#pragma unroll
            for (int c = 0; c < 2; c++) {
                const int off = col * CC + c * 32 + q * 8;
                Bh[c] = *(const f16x8*)(Xhi + off);
                Bl[c] = *(const f16x8*)(Xlo + off);
            }
#pragma unroll
            for (int rt = 0; rt < 4; rt++) {
#pragma unroll
                for (int c = 0; c < 2; c++) {
                    acc[rt][ct] = __builtin_amdgcn_mfma_f32_16x16x32_f16(Al[rt][c], Bh[c], acc[rt][ct], 0, 0, 0);
                    acc[rt][ct] = __builtin_amdgcn_mfma_f32_16x16x32_f16(Ah[rt][c], Bl[c], acc[rt][ct], 0, 0, 0);
                    acc[rt][ct] = __builtin_amdgcn_mfma_f32_16x16x32_f16(Ah[rt][c], Bh[c], acc[rt][ct], 0, 0, 0);
                }
            }
        }

        // per-lane column coords for the 4 contiguous cols of this jt
        int rj[4], cj[4];
#pragma unroll
        for (int ct = 0; ct < 4; ct++) {
            const int j = jb + ct;
            rj[ct] = j / HH;
            cj[ct] = j - rj[ct] * HH;
        }
#pragma unroll
        for (int rt = 0; rt < 4; rt++) {
#pragma unroll
            for (int r = 0; r < 4; r++) {
                const int il = wave * 64 + rt * 16 + q * 4 + r;
                const int i = i0 + il;
                const float mhv = sMh[il], rden = sRden[il], rec = sRec[il];
                const int rc = sRC[il];
                const int ri = rc >> 8, ci = rc & 255;
                float4v as4, ad4;
#pragma unroll
                for (int ct = 0; ct < 4; ct++) {
                    float e = __expf(acc[rt][ct][r] - mhv) * rden;
                    if (e < THR) e = 0.f;   // As < 1/N -> 0 (avg == 1/N)
                    as4[ct] = e;
                    const int dr = ri - rj[ct], dc = ci - cj[ct];
                    const float d2 = (float)(dr * dr + dc * dc);
                    float ad = __expf(-0.5f * d2) * rec;
                    if (i == jb + ct) ad = 0.f;   // diagonal stays 0
                    ad4[ct] = ad;
                }
                *(float4v*)(As + (size_t)i * NN + jb) = as4;
                *(float4v*)(Ad + (size_t)i * NN + jb) = ad4;
            }
        }
    }
}

extern "C" void kernel_launch(void* const* d_in, const int* in_sizes, int n_in,
                              void* d_out, int out_size, void* d_ws, size_t ws_size,
                              hipStream_t stream) {
    const float* X = (const float*)d_in[0];
    float* Ad = (float*)d_out;                    // output 0: [N,N]
    float* As = Ad + (size_t)NN * NN;             // output 1: [N,N]

    // workspace layout (exactly 1689604 B — tight; do not extend)
    char* w = (char*)d_ws;
    _Float16* Xhi = (_Float16*)(w);               // 819200 B
    _Float16* Xlo = (_Float16*)(w + 819200);      // 819200 B
    float* norms  = (float*)(w + 1638400);        // 25600 B
    float* denom  = (float*)(w + 1664000);        // 25600 B
    int*   nmax   = (int*)(w + 1689600);          // 4 B

    prep_kernel<<<dim3((NN * CC) / 1024), dim3(256), 0, stream>>>(
        X, Xhi, Xlo, norms, denom, nmax);
    pass1_kernel<<<dim3(25, 25), dim3(256), 0, stream>>>(
        Xhi, Xlo, norms, nmax, denom);
    pass2_kernel<<<dim3(25, 25), dim3(256), 0, stream>>>(
        Xhi, Xlo, norms, nmax, denom, Ad, As);
}